// Round 6
// baseline (142.216 us; speedup 1.0000x reference)
//
#include <hip/hip_runtime.h>

// pos/seq_lens fill for ragged batch metadata.
// d_out layout (int32): [0, num_tokens) = pos, [num_tokens, +max_num_reqs) = seq_lens.
//
// R6: single fused launch. R5 post-mortem: nontemporal stores were the win
// (L2 write-allocate churn was the R2-R3 40us limiter, not the searches:
// R2==R3 proved search cost ~0). So the prep kernel's precompute is dead
// weight (~3.5us dispatch + dependency). Fused design:
//  - pos blocks (16384 x 256 thr, 1 int4/thread): each lane binary-searches
//    its own first token over qsl (13 steps, wave-convergent addresses ->
//    L1 broadcast), computes base = nct[idx_mapping[r]] - qsl[r] per lane
//    (broadcast loads on single-request waves), while-advance across
//    intra-int4 request boundaries, then one nontemporal int4 store.
//  - tail blocks write seq_lens (incl. zero tail past num_reqs).

#define TPB 256
#define TILE_TOK 1024                       // tokens per pos block
#define SEQ_PER_BLOCK (TPB * 4)             // 1024

typedef int vint4 __attribute__((ext_vector_type(4)));

__global__ __launch_bounds__(TPB) void fused_kernel(
    const int* __restrict__ idx_mapping,
    const int* __restrict__ qsl,          // [num_reqs+1]
    const int* __restrict__ nct,          // [max_num_reqs]
    int* __restrict__ pos_out,            // [num_tokens]
    int* __restrict__ seq_out,            // [max_num_reqs]
    int num_reqs, int max_num_reqs, int num_tokens,
    int pos_blocks)
{
    int b = blockIdx.x;

    if (b >= pos_blocks) {
        // ---- seq_lens ----
        int i = (b - pos_blocks) * SEQ_PER_BLOCK + (int)threadIdx.x * 4;
        if (i >= max_num_reqs) return;
        vint4 v;
        #pragma unroll
        for (int k = 0; k < 4; ++k) {
            int idx = i + k;
            int val = 0;
            if (idx < num_reqs)
                val = nct[idx_mapping[idx]] + (qsl[idx + 1] - qsl[idx]);
            v[k] = val;
        }
        if (i + 4 <= max_num_reqs) {
            *(vint4*)(seq_out + i) = v;
        } else {
            for (int k = 0; k < max_num_reqs - i; ++k) seq_out[i + k] = v[k];
        }
        return;
    }

    // ---- pos ----
    int t = b * TILE_TOK + (int)threadIdx.x * 4;
    // clamp (no early return: keeps waves convergent; only last partial tile)
    int tc = (t < num_tokens) ? t : (num_tokens - 1);

    // upper_bound: last r in [0, num_reqs] with qsl[r] <= tc.
    // Addresses are wave-convergent for the first ~11 of 13 steps -> L1
    // broadcast; qsl (32 KB) is L1/L2 resident.
    int l = 0, h = num_reqs + 1;
    while (h - l > 1) {
        int mid = (l + h) >> 1;
        if (qsl[mid] <= tc) l = mid; else h = mid;
    }
    int r = l;
    int next = qsl[r + 1];
    int base = nct[idx_mapping[r]] - qsl[r];   // broadcast loads on uniform waves

    vint4 v;
    #pragma unroll
    for (int k = 0; k < 4; ++k) {
        int tk = t + k;
        while (tk >= next && r < num_reqs - 1) {   // crosses boundary (rare)
            ++r;
            next = qsl[r + 1];
            base = nct[idx_mapping[r]] - qsl[r];
        }
        v[k] = base + tk;
    }

    if (t + 4 <= num_tokens) {
        __builtin_nontemporal_store(v, (vint4*)(pos_out + t));
    } else {
        for (int k = 0; k < num_tokens - t; ++k) pos_out[t + k] = v[k];
    }
}

extern "C" void kernel_launch(void* const* d_in, const int* in_sizes, int n_in,
                              void* d_out, int out_size, void* d_ws, size_t ws_size,
                              hipStream_t stream) {
    const int* idx_mapping = (const int*)d_in[0];
    const int* qsl         = (const int*)d_in[1];
    const int* nct         = (const int*)d_in[2];
    // d_in[3] (pos buffer) and d_in[4] (seq_lens buffer) are unused inputs.

    int num_reqs     = in_sizes[0];
    int max_num_reqs = in_sizes[2];
    int num_tokens   = in_sizes[3];

    int* out = (int*)d_out;
    int* pos_out = out;
    int* seq_out = out + num_tokens;

    int pos_blocks = (int)(((long long)num_tokens + TILE_TOK - 1) / TILE_TOK);  // 16384
    int seq_blocks = (max_num_reqs + SEQ_PER_BLOCK - 1) / SEQ_PER_BLOCK;        // 16

    fused_kernel<<<dim3(pos_blocks + seq_blocks), dim3(TPB), 0, stream>>>(
        idx_mapping, qsl, nct, pos_out, seq_out,
        num_reqs, max_num_reqs, num_tokens, pos_blocks);
}

// Round 7
// 120.200 us; speedup vs baseline: 1.1832x; 1.1832x over previous
//
#include <hip/hip_runtime.h>

// pos/seq_lens fill for ragged batch metadata.
// d_out layout (int32): [0, num_tokens) = pos, [num_tokens, +max_num_reqs) = seq_lens.
//
// R7: invert the parallelization -- one block per REQUEST, zero searches.
// Evidence: R6 (per-lane 13-step search + NT stores) = 44us, R5 (precomputed
// search + NT stores) = ~15us+3.5us prep, R2/R3 = ~40us floor from L2
// write-allocate (killed by NT stores in R5). The search side is the only
// remaining cost; per-request blocks need just 4 wave-uniform scalar loads.
//  - Block r: start=qsl[r], end=qsl[r+1], base=nct[idx_mapping[r]]-start;
//    stream pos[t]=base+t over [start,end) with aligned NT int4 stores
//    (scalar head/tail for 16B alignment).
//  - Straggler bound: max request ~ avg*ln(8192) ~ 18K tokens -> ~72KB for
//    one block, ~1-2us tail. Acceptable.
//  - 16 tail blocks write seq_lens vectorized (incl. zeros past num_reqs --
//    harness poisons d_out with 0xAA).

#define TPB 256
#define SEQ_PER_BLOCK (TPB * 4)             // 1024

typedef int vint4 __attribute__((ext_vector_type(4)));

__global__ __launch_bounds__(TPB) void fused_kernel(
    const int* __restrict__ idx_mapping,
    const int* __restrict__ qsl,          // [num_reqs+1]
    const int* __restrict__ nct,          // [max_num_reqs]
    int* __restrict__ pos_out,            // [num_tokens]
    int* __restrict__ seq_out,            // [max_num_reqs]
    int num_reqs, int max_num_reqs)
{
    int b = blockIdx.x;
    int tid = (int)threadIdx.x;

    if (b >= num_reqs) {
        // ---- seq_lens ----
        int i = (b - num_reqs) * SEQ_PER_BLOCK + tid * 4;
        if (i >= max_num_reqs) return;
        vint4 v;
        #pragma unroll
        for (int k = 0; k < 4; ++k) {
            int idx = i + k;
            int val = 0;
            if (idx < num_reqs)
                val = nct[idx_mapping[idx]] + (qsl[idx + 1] - qsl[idx]);
            v[k] = val;
        }
        if (i + 4 <= max_num_reqs) {
            *(vint4*)(seq_out + i) = v;
        } else {
            for (int k = 0; k < max_num_reqs - i; ++k) seq_out[i + k] = v[k];
        }
        return;
    }

    // ---- pos: stream one request's range ----
    int r = b;
    int start = qsl[r];                   // wave-uniform -> s_load
    int end   = qsl[r + 1];
    if (start >= end) return;             // empty request
    int base  = nct[idx_mapping[r]] - start;

    // head: up to 3 tokens until 16B alignment
    int a = (start + 3) & ~3;
    if (a > end) a = end;
    if (tid < a - start) pos_out[start + tid] = base + start + tid;

    // body: aligned int4 NT stores
    int e4 = a + ((end - a) & ~3);
    for (int t = a + tid * 4; t < e4; t += TPB * 4) {
        vint4 v;
        v[0] = base + t;     v[1] = base + t + 1;
        v[2] = base + t + 2; v[3] = base + t + 3;
        __builtin_nontemporal_store(v, (vint4*)(pos_out + t));
    }

    // tail: up to 3 tokens
    if (tid < end - e4) pos_out[e4 + tid] = base + e4 + tid;
}

extern "C" void kernel_launch(void* const* d_in, const int* in_sizes, int n_in,
                              void* d_out, int out_size, void* d_ws, size_t ws_size,
                              hipStream_t stream) {
    const int* idx_mapping = (const int*)d_in[0];
    const int* qsl         = (const int*)d_in[1];
    const int* nct         = (const int*)d_in[2];
    // d_in[3] (pos buffer) and d_in[4] (seq_lens buffer) are unused inputs.

    int num_reqs     = in_sizes[0];
    int max_num_reqs = in_sizes[2];
    int num_tokens   = in_sizes[3];

    int* out = (int*)d_out;
    int* pos_out = out;
    int* seq_out = out + num_tokens;

    int seq_blocks = (max_num_reqs + SEQ_PER_BLOCK - 1) / SEQ_PER_BLOCK;   // 16

    fused_kernel<<<dim3(num_reqs + seq_blocks), dim3(TPB), 0, stream>>>(
        idx_mapping, qsl, nct, pos_out, seq_out, num_reqs, max_num_reqs);
}